// Round 1
// baseline (3762.826 us; speedup 1.0000x reference)
//
#include <hip/hip_runtime.h>

#define E_TOTAL 800000
#define N_TOTAL 50000

constexpr int ET = 32;      // edges per block
constexpr int NT = 32;      // nodes per block
constexpr int XPAD = 292;   // 288 + 4 (bank-conflict pad, keeps 16B align)
constexpr int NPAD = 260;   // 256 + 4
constexpr int HPAD = 132;   // 128 + 4

// ---------------- Edge MLP + scatter-add ----------------
__global__ __launch_bounds__(256, 2)
void edge_mlp(const float* __restrict__ h,
              const int* __restrict__ ei,    // [2][E]
              const float* __restrict__ ea,  // [E][32]
              const float* __restrict__ W1,  // [288][128]
              const float* __restrict__ b1,
              const float* __restrict__ W2,  // [128][128]
              const float* __restrict__ b2,
              float* __restrict__ mi)        // [N][128] accumulator
{
    __shared__ float sX[ET * XPAD];
    __shared__ float sH[ET * HPAD];
    __shared__ int   sDst[ET];

    const int tid = threadIdx.x;
    const int e0  = blockIdx.x * ET;

    if (tid < ET) sDst[tid] = ei[E_TOTAL + e0 + tid];

    // gather edge_input = [h[src] | h[dst] | ea] : 72 float4 per edge
    const float4* h4  = (const float4*)h;
    const float4* ea4 = (const float4*)ea;
    for (int idx = tid; idx < ET * 72; idx += 256) {
        const int e  = idx / 72;
        const int c  = idx - e * 72;
        const int ge = e0 + e;
        float4 v;
        if (c < 32)      v = h4[(size_t)ei[ge] * 32 + c];
        else if (c < 64) v = h4[(size_t)ei[E_TOTAL + ge] * 32 + (c - 32)];
        else             v = ea4[(size_t)ge * 8 + (c - 64)];
        *(float4*)(&sX[e * XPAD + c * 4]) = v;
    }
    __syncthreads();

    const int tx = tid & 15;   // 16 col-groups of 8 cols
    const int ty = tid >> 4;   // 16 row-groups of 2 rows
    const int j0 = tx * 8;
    const int r0 = ty * 2;

    // ---- GEMM1: K=288, relu ----
    float acc[2][8];
    #pragma unroll
    for (int r = 0; r < 2; ++r)
        #pragma unroll
        for (int c = 0; c < 8; ++c) acc[r][c] = 0.f;

    for (int k = 0; k < 288; k += 4) {
        float4 a[2];
        #pragma unroll
        for (int r = 0; r < 2; ++r)
            a[r] = *(const float4*)(&sX[(r0 + r) * XPAD + k]);
        float4 w[4][2];
        #pragma unroll
        for (int kk = 0; kk < 4; ++kk) {
            const float4* wp = (const float4*)(&W1[(k + kk) * 128 + j0]);
            w[kk][0] = wp[0];
            w[kk][1] = wp[1];
        }
        #pragma unroll
        for (int kk = 0; kk < 4; ++kk) {
            const float* wf = (const float*)&w[kk][0];
            #pragma unroll
            for (int r = 0; r < 2; ++r) {
                const float av = ((const float*)&a[r])[kk];
                #pragma unroll
                for (int c = 0; c < 8; ++c)
                    acc[r][c] = fmaf(av, wf[c], acc[r][c]);
            }
        }
    }

    float bias[8];
    *(float4*)&bias[0] = *(const float4*)&b1[j0];
    *(float4*)&bias[4] = *(const float4*)&b1[j0 + 4];

    #pragma unroll
    for (int r = 0; r < 2; ++r) {
        float4 v0, v1;
        v0.x = fmaxf(acc[r][0] + bias[0], 0.f);
        v0.y = fmaxf(acc[r][1] + bias[1], 0.f);
        v0.z = fmaxf(acc[r][2] + bias[2], 0.f);
        v0.w = fmaxf(acc[r][3] + bias[3], 0.f);
        v1.x = fmaxf(acc[r][4] + bias[4], 0.f);
        v1.y = fmaxf(acc[r][5] + bias[5], 0.f);
        v1.z = fmaxf(acc[r][6] + bias[6], 0.f);
        v1.w = fmaxf(acc[r][7] + bias[7], 0.f);
        *(float4*)(&sH[(r0 + r) * HPAD + j0])     = v0;
        *(float4*)(&sH[(r0 + r) * HPAD + j0 + 4]) = v1;
    }
    __syncthreads();

    // ---- GEMM2: K=128 ----
    float acc2[2][8];
    #pragma unroll
    for (int r = 0; r < 2; ++r)
        #pragma unroll
        for (int c = 0; c < 8; ++c) acc2[r][c] = 0.f;

    for (int k = 0; k < 128; k += 4) {
        float4 a[2];
        #pragma unroll
        for (int r = 0; r < 2; ++r)
            a[r] = *(const float4*)(&sH[(r0 + r) * HPAD + k]);
        float4 w[4][2];
        #pragma unroll
        for (int kk = 0; kk < 4; ++kk) {
            const float4* wp = (const float4*)(&W2[(k + kk) * 128 + j0]);
            w[kk][0] = wp[0];
            w[kk][1] = wp[1];
        }
        #pragma unroll
        for (int kk = 0; kk < 4; ++kk) {
            const float* wf = (const float*)&w[kk][0];
            #pragma unroll
            for (int r = 0; r < 2; ++r) {
                const float av = ((const float*)&a[r])[kk];
                #pragma unroll
                for (int c = 0; c < 8; ++c)
                    acc2[r][c] = fmaf(av, wf[c], acc2[r][c]);
            }
        }
    }

    float bias2[8];
    *(float4*)&bias2[0] = *(const float4*)&b2[j0];
    *(float4*)&bias2[4] = *(const float4*)&b2[j0 + 4];

    #pragma unroll
    for (int r = 0; r < 2; ++r) {
        const int dst = sDst[r0 + r];
        float* mrow = &mi[(size_t)dst * 128 + j0];
        #pragma unroll
        for (int c = 0; c < 8; ++c)
            atomicAdd(&mrow[c], acc2[r][c] + bias2[c]);
    }
}

// ---------------- Node MLP ----------------
__global__ __launch_bounds__(256, 2)
void node_mlp(const float* __restrict__ h,
              const float* __restrict__ mi,
              const float* __restrict__ W1,  // [256][128]
              const float* __restrict__ b1,
              const float* __restrict__ W2,  // [128][128]
              const float* __restrict__ b2,
              float* __restrict__ out)       // [N][128]
{
    __shared__ float sX[NT * NPAD];
    __shared__ float sH[NT * HPAD];

    const int tid = threadIdx.x;
    const int n0  = blockIdx.x * NT;

    // gather node_input = [h[n] | mi[n]] : 64 float4 per node (in-place safe:
    // all reads staged to LDS before any write to out)
    const float4* h4  = (const float4*)h;
    const float4* mi4 = (const float4*)mi;
    for (int idx = tid; idx < NT * 64; idx += 256) {
        const int n  = idx >> 6;
        const int c  = idx & 63;
        const int gn = n0 + n;
        float4 v = make_float4(0.f, 0.f, 0.f, 0.f);
        if (gn < N_TOTAL) {
            if (c < 32) v = h4[(size_t)gn * 32 + c];
            else        v = mi4[(size_t)gn * 32 + (c - 32)];
        }
        *(float4*)(&sX[n * NPAD + c * 4]) = v;
    }
    __syncthreads();

    const int tx = tid & 15;
    const int ty = tid >> 4;
    const int j0 = tx * 8;
    const int r0 = ty * 2;

    // ---- GEMM1: K=256, relu ----
    float acc[2][8];
    #pragma unroll
    for (int r = 0; r < 2; ++r)
        #pragma unroll
        for (int c = 0; c < 8; ++c) acc[r][c] = 0.f;

    for (int k = 0; k < 256; k += 4) {
        float4 a[2];
        #pragma unroll
        for (int r = 0; r < 2; ++r)
            a[r] = *(const float4*)(&sX[(r0 + r) * NPAD + k]);
        float4 w[4][2];
        #pragma unroll
        for (int kk = 0; kk < 4; ++kk) {
            const float4* wp = (const float4*)(&W1[(k + kk) * 128 + j0]);
            w[kk][0] = wp[0];
            w[kk][1] = wp[1];
        }
        #pragma unroll
        for (int kk = 0; kk < 4; ++kk) {
            const float* wf = (const float*)&w[kk][0];
            #pragma unroll
            for (int r = 0; r < 2; ++r) {
                const float av = ((const float*)&a[r])[kk];
                #pragma unroll
                for (int c = 0; c < 8; ++c)
                    acc[r][c] = fmaf(av, wf[c], acc[r][c]);
            }
        }
    }

    float bias[8];
    *(float4*)&bias[0] = *(const float4*)&b1[j0];
    *(float4*)&bias[4] = *(const float4*)&b1[j0 + 4];

    #pragma unroll
    for (int r = 0; r < 2; ++r) {
        float4 v0, v1;
        v0.x = fmaxf(acc[r][0] + bias[0], 0.f);
        v0.y = fmaxf(acc[r][1] + bias[1], 0.f);
        v0.z = fmaxf(acc[r][2] + bias[2], 0.f);
        v0.w = fmaxf(acc[r][3] + bias[3], 0.f);
        v1.x = fmaxf(acc[r][4] + bias[4], 0.f);
        v1.y = fmaxf(acc[r][5] + bias[5], 0.f);
        v1.z = fmaxf(acc[r][6] + bias[6], 0.f);
        v1.w = fmaxf(acc[r][7] + bias[7], 0.f);
        *(float4*)(&sH[(r0 + r) * HPAD + j0])     = v0;
        *(float4*)(&sH[(r0 + r) * HPAD + j0 + 4]) = v1;
    }
    __syncthreads();

    // ---- GEMM2: K=128 ----
    float acc2[2][8];
    #pragma unroll
    for (int r = 0; r < 2; ++r)
        #pragma unroll
        for (int c = 0; c < 8; ++c) acc2[r][c] = 0.f;

    for (int k = 0; k < 128; k += 4) {
        float4 a[2];
        #pragma unroll
        for (int r = 0; r < 2; ++r)
            a[r] = *(const float4*)(&sH[(r0 + r) * HPAD + k]);
        float4 w[4][2];
        #pragma unroll
        for (int kk = 0; kk < 4; ++kk) {
            const float4* wp = (const float4*)(&W2[(k + kk) * 128 + j0]);
            w[kk][0] = wp[0];
            w[kk][1] = wp[1];
        }
        #pragma unroll
        for (int kk = 0; kk < 4; ++kk) {
            const float* wf = (const float*)&w[kk][0];
            #pragma unroll
            for (int r = 0; r < 2; ++r) {
                const float av = ((const float*)&a[r])[kk];
                #pragma unroll
                for (int c = 0; c < 8; ++c)
                    acc2[r][c] = fmaf(av, wf[c], acc2[r][c]);
            }
        }
    }

    float bias2[8];
    *(float4*)&bias2[0] = *(const float4*)&b2[j0];
    *(float4*)&bias2[4] = *(const float4*)&b2[j0 + 4];

    #pragma unroll
    for (int r = 0; r < 2; ++r) {
        const int gn = n0 + r0 + r;
        if (gn < N_TOTAL) {
            float4 v0, v1;
            v0.x = acc2[r][0] + bias2[0];
            v0.y = acc2[r][1] + bias2[1];
            v0.z = acc2[r][2] + bias2[2];
            v0.w = acc2[r][3] + bias2[3];
            v1.x = acc2[r][4] + bias2[4];
            v1.y = acc2[r][5] + bias2[5];
            v1.z = acc2[r][6] + bias2[6];
            v1.w = acc2[r][7] + bias2[7];
            *(float4*)(&out[(size_t)gn * 128 + j0])     = v0;
            *(float4*)(&out[(size_t)gn * 128 + j0 + 4]) = v1;
        }
    }
}

extern "C" void kernel_launch(void* const* d_in, const int* in_sizes, int n_in,
                              void* d_out, int out_size, void* d_ws, size_t ws_size,
                              hipStream_t stream) {
    const float* h   = (const float*)d_in[0];
    const int*   ei  = (const int*)d_in[1];
    const float* ea  = (const float*)d_in[2];
    const float* We1 = (const float*)d_in[3];
    const float* be1 = (const float*)d_in[4];
    const float* We2 = (const float*)d_in[5];
    const float* be2 = (const float*)d_in[6];
    const float* Wh1 = (const float*)d_in[7];
    const float* bh1 = (const float*)d_in[8];
    const float* Wh2 = (const float*)d_in[9];
    const float* bh2 = (const float*)d_in[10];
    float* out = (float*)d_out;

    const size_t need = (size_t)N_TOTAL * 128 * sizeof(float);
    float* mi = (ws_size >= need) ? (float*)d_ws : out;

    hipMemsetAsync(mi, 0, need, stream);
    edge_mlp<<<E_TOTAL / ET, 256, 0, stream>>>(h, ei, ea, We1, be1, We2, be2, mi);
    node_mlp<<<(N_TOTAL + NT - 1) / NT, 256, 0, stream>>>(h, mi, Wh1, bh1, Wh2, bh2, out);
}

// Round 2
// 1004.682 us; speedup vs baseline: 3.7453x; 3.7453x over previous
//
#include <hip/hip_runtime.h>

#define E_TOTAL 800000
#define N_TOTAL 50000

typedef __attribute__((ext_vector_type(8))) short short8;
typedef __attribute__((ext_vector_type(4))) float floatx4;

__device__ __forceinline__ unsigned short f2bf(float f) {
    union { float f; unsigned u; } x; x.f = f;
    unsigned r = x.u + 0x7fff + ((x.u >> 16) & 1);   // RNE
    return (unsigned short)(r >> 16);
}

// ---------------- weight transpose + bf16 convert (N==128) ----------------
__global__ void transpose_cvt(const float* __restrict__ W,
                              unsigned short* __restrict__ Wt, int K) {
    int t = blockIdx.x * 256 + threadIdx.x;
    if (t < K * 128) {
        int k = t >> 7, n = t & 127;
        Wt[n * K + k] = f2bf(W[t]);
    }
}

// ================= MFMA path =================
constexpr int XK = 296;  // 288 + 8 pad (stride 592B: 16B-aligned, 2-way banks)
constexpr int HK = 136;  // 128 + 8 pad (stride 272B)
constexpr int NK = 264;  // 256 + 8 pad (stride 528B)

__global__ __launch_bounds__(256, 2)
void edge_mfma(const float* __restrict__ h,
               const int* __restrict__ ei,
               const float* __restrict__ ea,
               const unsigned short* __restrict__ W1t,  // [128][288] bf16
               const float* __restrict__ b1,
               const unsigned short* __restrict__ W2t,  // [128][128] bf16
               const float* __restrict__ b2,
               float* __restrict__ mi)
{
    __shared__ unsigned short sX[64 * XK];
    __shared__ unsigned short sH[64 * HK];
    __shared__ int sDst[64];

    const int tid = threadIdx.x;
    const int e0  = blockIdx.x * 64;
    if (tid < 64) sDst[tid] = ei[E_TOTAL + e0 + tid];

    // gather + fp32->bf16 convert into LDS: 72 float4-groups per edge
    const float4* h4  = (const float4*)h;
    const float4* ea4 = (const float4*)ea;
    for (int idx = tid; idx < 64 * 72; idx += 256) {
        const int e  = idx / 72;
        const int c  = idx - e * 72;
        const int ge = e0 + e;
        float4 v;
        if (c < 32)      v = h4[(size_t)ei[ge] * 32 + c];
        else if (c < 64) v = h4[(size_t)ei[E_TOTAL + ge] * 32 + (c - 32)];
        else             v = ea4[(size_t)ge * 8 + (c - 64)];
        unsigned short* p = &sX[e * XK + c * 4];
        p[0] = f2bf(v.x); p[1] = f2bf(v.y); p[2] = f2bf(v.z); p[3] = f2bf(v.w);
    }
    __syncthreads();

    const int lane = tid & 63;
    const int w    = tid >> 6;
    const int q    = lane >> 4;
    const int lr   = lane & 15;
    const int n0   = w * 32;            // this wave's 32-col slice

    // ---- GEMM1: [64 x 288] @ [288 x 128], relu ----
    floatx4 acc[4][2];
    #pragma unroll
    for (int mt = 0; mt < 4; ++mt)
        #pragma unroll
        for (int nt = 0; nt < 2; ++nt)
            acc[mt][nt] = (floatx4){0.f, 0.f, 0.f, 0.f};

    #pragma unroll
    for (int ks = 0; ks < 9; ++ks) {
        const int kb = ks * 32 + q * 8;
        short8 a[4], b[2];
        #pragma unroll
        for (int mt = 0; mt < 4; ++mt)
            a[mt] = *(const short8*)(&sX[(mt * 16 + lr) * XK + kb]);
        #pragma unroll
        for (int nt = 0; nt < 2; ++nt)
            b[nt] = *(const short8*)(&W1t[(n0 + nt * 16 + lr) * 288 + kb]);
        #pragma unroll
        for (int mt = 0; mt < 4; ++mt)
            #pragma unroll
            for (int nt = 0; nt < 2; ++nt)
                acc[mt][nt] = __builtin_amdgcn_mfma_f32_16x16x32_bf16(
                    a[mt], b[nt], acc[mt][nt], 0, 0, 0);
    }

    {
        float bias[2] = { b1[n0 + lr], b1[n0 + 16 + lr] };
        #pragma unroll
        for (int mt = 0; mt < 4; ++mt)
            #pragma unroll
            for (int nt = 0; nt < 2; ++nt)
                #pragma unroll
                for (int r = 0; r < 4; ++r) {
                    float v = fmaxf(acc[mt][nt][r] + bias[nt], 0.f);
                    sH[(mt * 16 + q * 4 + r) * HK + n0 + nt * 16 + lr] = f2bf(v);
                }
    }
    __syncthreads();

    // ---- GEMM2: [64 x 128] @ [128 x 128] ----
    floatx4 acc2[4][2];
    #pragma unroll
    for (int mt = 0; mt < 4; ++mt)
        #pragma unroll
        for (int nt = 0; nt < 2; ++nt)
            acc2[mt][nt] = (floatx4){0.f, 0.f, 0.f, 0.f};

    #pragma unroll
    for (int ks = 0; ks < 4; ++ks) {
        const int kb = ks * 32 + q * 8;
        short8 a[4], b[2];
        #pragma unroll
        for (int mt = 0; mt < 4; ++mt)
            a[mt] = *(const short8*)(&sH[(mt * 16 + lr) * HK + kb]);
        #pragma unroll
        for (int nt = 0; nt < 2; ++nt)
            b[nt] = *(const short8*)(&W2t[(n0 + nt * 16 + lr) * 128 + kb]);
        #pragma unroll
        for (int mt = 0; mt < 4; ++mt)
            #pragma unroll
            for (int nt = 0; nt < 2; ++nt)
                acc2[mt][nt] = __builtin_amdgcn_mfma_f32_16x16x32_bf16(
                    a[mt], b[nt], acc2[mt][nt], 0, 0, 0);
    }

    {
        float bias[2] = { b2[n0 + lr], b2[n0 + 16 + lr] };
        #pragma unroll
        for (int mt = 0; mt < 4; ++mt)
            #pragma unroll
            for (int r = 0; r < 4; ++r) {
                const int m   = mt * 16 + q * 4 + r;
                const int dst = sDst[m];
                float* row = &mi[(size_t)dst * 128];
                #pragma unroll
                for (int nt = 0; nt < 2; ++nt)
                    atomicAdd(&row[n0 + nt * 16 + lr], acc2[mt][nt][r] + bias[nt]);
            }
    }
}

__global__ __launch_bounds__(256, 2)
void node_mfma(const float* __restrict__ h,
               const float* __restrict__ mi,
               const unsigned short* __restrict__ W1t,  // [128][256] bf16
               const float* __restrict__ b1,
               const unsigned short* __restrict__ W2t,  // [128][128] bf16
               const float* __restrict__ b2,
               float* __restrict__ out)
{
    __shared__ unsigned short sX[64 * NK];
    __shared__ unsigned short sH[64 * HK];

    const int tid = threadIdx.x;
    const int g0  = blockIdx.x * 64;

    const float4* h4  = (const float4*)h;
    const float4* mi4 = (const float4*)mi;
    for (int idx = tid; idx < 64 * 64; idx += 256) {
        const int n  = idx >> 6;
        const int c  = idx & 63;
        const int gn = g0 + n;
        float4 v = make_float4(0.f, 0.f, 0.f, 0.f);
        if (gn < N_TOTAL)
            v = (c < 32) ? h4[(size_t)gn * 32 + c] : mi4[(size_t)gn * 32 + (c - 32)];
        unsigned short* p = &sX[n * NK + c * 4];
        p[0] = f2bf(v.x); p[1] = f2bf(v.y); p[2] = f2bf(v.z); p[3] = f2bf(v.w);
    }
    __syncthreads();

    const int lane = tid & 63;
    const int w    = tid >> 6;
    const int q    = lane >> 4;
    const int lr   = lane & 15;
    const int n0   = w * 32;

    floatx4 acc[4][2];
    #pragma unroll
    for (int mt = 0; mt < 4; ++mt)
        #pragma unroll
        for (int nt = 0; nt < 2; ++nt)
            acc[mt][nt] = (floatx4){0.f, 0.f, 0.f, 0.f};

    #pragma unroll
    for (int ks = 0; ks < 8; ++ks) {
        const int kb = ks * 32 + q * 8;
        short8 a[4], b[2];
        #pragma unroll
        for (int mt = 0; mt < 4; ++mt)
            a[mt] = *(const short8*)(&sX[(mt * 16 + lr) * NK + kb]);
        #pragma unroll
        for (int nt = 0; nt < 2; ++nt)
            b[nt] = *(const short8*)(&W1t[(n0 + nt * 16 + lr) * 256 + kb]);
        #pragma unroll
        for (int mt = 0; mt < 4; ++mt)
            #pragma unroll
            for (int nt = 0; nt < 2; ++nt)
                acc[mt][nt] = __builtin_amdgcn_mfma_f32_16x16x32_bf16(
                    a[mt], b[nt], acc[mt][nt], 0, 0, 0);
    }

    {
        float bias[2] = { b1[n0 + lr], b1[n0 + 16 + lr] };
        #pragma unroll
        for (int mt = 0; mt < 4; ++mt)
            #pragma unroll
            for (int nt = 0; nt < 2; ++nt)
                #pragma unroll
                for (int r = 0; r < 4; ++r) {
                    float v = fmaxf(acc[mt][nt][r] + bias[nt], 0.f);
                    sH[(mt * 16 + q * 4 + r) * HK + n0 + nt * 16 + lr] = f2bf(v);
                }
    }
    __syncthreads();

    floatx4 acc2[4][2];
    #pragma unroll
    for (int mt = 0; mt < 4; ++mt)
        #pragma unroll
        for (int nt = 0; nt < 2; ++nt)
            acc2[mt][nt] = (floatx4){0.f, 0.f, 0.f, 0.f};

    #pragma unroll
    for (int ks = 0; ks < 4; ++ks) {
        const int kb = ks * 32 + q * 8;
        short8 a[4], b[2];
        #pragma unroll
        for (int mt = 0; mt < 4; ++mt)
            a[mt] = *(const short8*)(&sH[(mt * 16 + lr) * HK + kb]);
        #pragma unroll
        for (int nt = 0; nt < 2; ++nt)
            b[nt] = *(const short8*)(&W2t[(n0 + nt * 16 + lr) * 128 + kb]);
        #pragma unroll
        for (int mt = 0; mt < 4; ++mt)
            #pragma unroll
            for (int nt = 0; nt < 2; ++nt)
                acc2[mt][nt] = __builtin_amdgcn_mfma_f32_16x16x32_bf16(
                    a[mt], b[nt], acc2[mt][nt], 0, 0, 0);
    }

    {
        float bias[2] = { b2[n0 + lr], b2[n0 + 16 + lr] };
        #pragma unroll
        for (int mt = 0; mt < 4; ++mt)
            #pragma unroll
            for (int r = 0; r < 4; ++r) {
                const int gm = g0 + mt * 16 + q * 4 + r;
                if (gm < N_TOTAL) {
                    #pragma unroll
                    for (int nt = 0; nt < 2; ++nt)
                        out[(size_t)gm * 128 + n0 + nt * 16 + lr] =
                            acc2[mt][nt][r] + bias[nt];
                }
            }
    }
}

// ================= fp32 fallback path (round-1, known-correct) =================
constexpr int ET = 32;
constexpr int NT = 32;
constexpr int XPADf = 292;
constexpr int NPADf = 260;
constexpr int HPADf = 132;

__global__ __launch_bounds__(256, 2)
void edge_mlp_f32(const float* __restrict__ h, const int* __restrict__ ei,
                  const float* __restrict__ ea, const float* __restrict__ W1,
                  const float* __restrict__ b1, const float* __restrict__ W2,
                  const float* __restrict__ b2, float* __restrict__ mi)
{
    __shared__ float sX[ET * XPADf];
    __shared__ float sH[ET * HPADf];
    __shared__ int   sDst[ET];
    const int tid = threadIdx.x;
    const int e0  = blockIdx.x * ET;
    if (tid < ET) sDst[tid] = ei[E_TOTAL + e0 + tid];
    const float4* h4  = (const float4*)h;
    const float4* ea4 = (const float4*)ea;
    for (int idx = tid; idx < ET * 72; idx += 256) {
        const int e = idx / 72, c = idx - e * 72, ge = e0 + e;
        float4 v;
        if (c < 32)      v = h4[(size_t)ei[ge] * 32 + c];
        else if (c < 64) v = h4[(size_t)ei[E_TOTAL + ge] * 32 + (c - 32)];
        else             v = ea4[(size_t)ge * 8 + (c - 64)];
        *(float4*)(&sX[e * XPADf + c * 4]) = v;
    }
    __syncthreads();
    const int tx = tid & 15, ty = tid >> 4, j0 = tx * 8, r0 = ty * 2;
    float acc[2][8];
    for (int r = 0; r < 2; ++r) for (int c = 0; c < 8; ++c) acc[r][c] = 0.f;
    for (int k = 0; k < 288; k += 4) {
        float4 a[2];
        for (int r = 0; r < 2; ++r) a[r] = *(const float4*)(&sX[(r0 + r) * XPADf + k]);
        float4 wv[4][2];
        for (int kk = 0; kk < 4; ++kk) {
            const float4* wp = (const float4*)(&W1[(k + kk) * 128 + j0]);
            wv[kk][0] = wp[0]; wv[kk][1] = wp[1];
        }
        for (int kk = 0; kk < 4; ++kk) {
            const float* wf = (const float*)&wv[kk][0];
            for (int r = 0; r < 2; ++r) {
                const float av = ((const float*)&a[r])[kk];
                for (int c = 0; c < 8; ++c) acc[r][c] = fmaf(av, wf[c], acc[r][c]);
            }
        }
    }
    float bias[8];
    *(float4*)&bias[0] = *(const float4*)&b1[j0];
    *(float4*)&bias[4] = *(const float4*)&b1[j0 + 4];
    for (int r = 0; r < 2; ++r)
        for (int c = 0; c < 8; ++c)
            sH[(r0 + r) * HPADf + j0 + c] = fmaxf(acc[r][c] + bias[c], 0.f);
    __syncthreads();
    float acc2[2][8];
    for (int r = 0; r < 2; ++r) for (int c = 0; c < 8; ++c) acc2[r][c] = 0.f;
    for (int k = 0; k < 128; k += 4) {
        float4 a[2];
        for (int r = 0; r < 2; ++r) a[r] = *(const float4*)(&sH[(r0 + r) * HPADf + k]);
        float4 wv[4][2];
        for (int kk = 0; kk < 4; ++kk) {
            const float4* wp = (const float4*)(&W2[(k + kk) * 128 + j0]);
            wv[kk][0] = wp[0]; wv[kk][1] = wp[1];
        }
        for (int kk = 0; kk < 4; ++kk) {
            const float* wf = (const float*)&wv[kk][0];
            for (int r = 0; r < 2; ++r) {
                const float av = ((const float*)&a[r])[kk];
                for (int c = 0; c < 8; ++c) acc2[r][c] = fmaf(av, wf[c], acc2[r][c]);
            }
        }
    }
    float bias2[8];
    *(float4*)&bias2[0] = *(const float4*)&b2[j0];
    *(float4*)&bias2[4] = *(const float4*)&b2[j0 + 4];
    for (int r = 0; r < 2; ++r) {
        const int dst = sDst[r0 + r];
        float* mrow = &mi[(size_t)dst * 128 + j0];
        for (int c = 0; c < 8; ++c) atomicAdd(&mrow[c], acc2[r][c] + bias2[c]);
    }
}

__global__ __launch_bounds__(256, 2)
void node_mlp_f32(const float* __restrict__ h, const float* __restrict__ mi,
                  const float* __restrict__ W1, const float* __restrict__ b1,
                  const float* __restrict__ W2, const float* __restrict__ b2,
                  float* __restrict__ out)
{
    __shared__ float sX[NT * NPADf];
    __shared__ float sH[NT * HPADf];
    const int tid = threadIdx.x;
    const int n0  = blockIdx.x * NT;
    const float4* h4  = (const float4*)h;
    const float4* mi4 = (const float4*)mi;
    for (int idx = tid; idx < NT * 64; idx += 256) {
        const int n = idx >> 6, c = idx & 63, gn = n0 + n;
        float4 v = make_float4(0.f, 0.f, 0.f, 0.f);
        if (gn < N_TOTAL)
            v = (c < 32) ? h4[(size_t)gn * 32 + c] : mi4[(size_t)gn * 32 + (c - 32)];
        *(float4*)(&sX[n * NPADf + c * 4]) = v;
    }
    __syncthreads();
    const int tx = tid & 15, ty = tid >> 4, j0 = tx * 8, r0 = ty * 2;
    float acc[2][8];
    for (int r = 0; r < 2; ++r) for (int c = 0; c < 8; ++c) acc[r][c] = 0.f;
    for (int k = 0; k < 256; k += 4) {
        float4 a[2];
        for (int r = 0; r < 2; ++r) a[r] = *(const float4*)(&sX[(r0 + r) * NPADf + k]);
        float4 wv[4][2];
        for (int kk = 0; kk < 4; ++kk) {
            const float4* wp = (const float4*)(&W1[(k + kk) * 128 + j0]);
            wv[kk][0] = wp[0]; wv[kk][1] = wp[1];
        }
        for (int kk = 0; kk < 4; ++kk) {
            const float* wf = (const float*)&wv[kk][0];
            for (int r = 0; r < 2; ++r) {
                const float av = ((const float*)&a[r])[kk];
                for (int c = 0; c < 8; ++c) acc[r][c] = fmaf(av, wf[c], acc[r][c]);
            }
        }
    }
    float bias[8];
    *(float4*)&bias[0] = *(const float4*)&b1[j0];
    *(float4*)&bias[4] = *(const float4*)&b1[j0 + 4];
    for (int r = 0; r < 2; ++r)
        for (int c = 0; c < 8; ++c)
            sH[(r0 + r) * HPADf + j0 + c] = fmaxf(acc[r][c] + bias[c], 0.f);
    __syncthreads();
    float acc2[2][8];
    for (int r = 0; r < 2; ++r) for (int c = 0; c < 8; ++c) acc2[r][c] = 0.f;
    for (int k = 0; k < 128; k += 4) {
        float4 a[2];
        for (int r = 0; r < 2; ++r) a[r] = *(const float4*)(&sH[(r0 + r) * HPADf + k]);
        float4 wv[4][2];
        for (int kk = 0; kk < 4; ++kk) {
            const float4* wp = (const float4*)(&W2[(k + kk) * 128 + j0]);
            wv[kk][0] = wp[0]; wv[kk][1] = wp[1];
        }
        for (int kk = 0; kk < 4; ++kk) {
            const float* wf = (const float*)&wv[kk][0];
            for (int r = 0; r < 2; ++r) {
                const float av = ((const float*)&a[r])[kk];
                for (int c = 0; c < 8; ++c) acc2[r][c] = fmaf(av, wf[c], acc2[r][c]);
            }
        }
    }
    float bias2[8];
    *(float4*)&bias2[0] = *(const float4*)&b2[j0];
    *(float4*)&bias2[4] = *(const float4*)&b2[j0 + 4];
    for (int r = 0; r < 2; ++r) {
        const int gn = n0 + r0 + r;
        if (gn < N_TOTAL) {
            for (int c = 0; c < 8; ++c)
                out[(size_t)gn * 128 + j0 + c] = acc2[r][c] + bias2[c];
        }
    }
}

extern "C" void kernel_launch(void* const* d_in, const int* in_sizes, int n_in,
                              void* d_out, int out_size, void* d_ws, size_t ws_size,
                              hipStream_t stream) {
    const float* h   = (const float*)d_in[0];
    const int*   ei  = (const int*)d_in[1];
    const float* ea  = (const float*)d_in[2];
    const float* We1 = (const float*)d_in[3];
    const float* be1 = (const float*)d_in[4];
    const float* We2 = (const float*)d_in[5];
    const float* be2 = (const float*)d_in[6];
    const float* Wh1 = (const float*)d_in[7];
    const float* bh1 = (const float*)d_in[8];
    const float* Wh2 = (const float*)d_in[9];
    const float* bh2 = (const float*)d_in[10];
    float* out = (float*)d_out;

    const size_t szMi   = (size_t)N_TOTAL * 128 * sizeof(float);      // 25.6 MB
    const size_t szW1t  = 128 * 288 * 2;
    const size_t szW2t  = 128 * 128 * 2;
    const size_t szWh1t = 128 * 256 * 2;
    const size_t szWh2t = 128 * 128 * 2;
    const size_t need   = szMi + szW1t + szW2t + szWh1t + szWh2t;

    if (ws_size >= need) {
        // ---- MFMA path ----
        char* wsb = (char*)d_ws;
        float* mi = (float*)wsb;
        unsigned short* W1t  = (unsigned short*)(wsb + szMi);
        unsigned short* W2t  = (unsigned short*)(wsb + szMi + szW1t);
        unsigned short* Wh1t = (unsigned short*)(wsb + szMi + szW1t + szW2t);
        unsigned short* Wh2t = (unsigned short*)(wsb + szMi + szW1t + szW2t + szWh1t);

        hipMemsetAsync(mi, 0, szMi, stream);
        transpose_cvt<<<(288 * 128 + 255) / 256, 256, 0, stream>>>(We1, W1t, 288);
        transpose_cvt<<<(128 * 128 + 255) / 256, 256, 0, stream>>>(We2, W2t, 128);
        transpose_cvt<<<(256 * 128 + 255) / 256, 256, 0, stream>>>(Wh1, Wh1t, 256);
        transpose_cvt<<<(128 * 128 + 255) / 256, 256, 0, stream>>>(Wh2, Wh2t, 128);

        edge_mfma<<<E_TOTAL / 64, 256, 0, stream>>>(h, ei, ea, W1t, be1, W2t, be2, mi);
        node_mfma<<<(N_TOTAL + 63) / 64, 256, 0, stream>>>(h, mi, Wh1t, bh1, Wh2t, bh2, out);
    } else {
        // ---- fp32 fallback ----
        float* mi = (ws_size >= szMi) ? (float*)d_ws : out;
        hipMemsetAsync(mi, 0, szMi, stream);
        edge_mlp_f32<<<E_TOTAL / ET, 256, 0, stream>>>(h, ei, ea, We1, be1, We2, be2, mi);
        node_mlp_f32<<<(N_TOTAL + NT - 1) / NT, 256, 0, stream>>>(h, mi, Wh1, bh1, Wh2, bh2, out);
    }
}

// Round 3
// 643.688 us; speedup vs baseline: 5.8457x; 1.5608x over previous
//
#include <hip/hip_runtime.h>

#define E_TOTAL 800000
#define N_TOTAL 50000

typedef __attribute__((ext_vector_type(8))) short short8;
typedef __attribute__((ext_vector_type(4))) float floatx4;

__device__ __forceinline__ unsigned short f2bf(float f) {
    union { float f; unsigned u; } x; x.f = f;
    unsigned r = x.u + 0x7fff + ((x.u >> 16) & 1);   // RNE
    return (unsigned short)(r >> 16);
}

// ---------------- weight transpose + bf16 convert (N==128) ----------------
__global__ void transpose_cvt(const float* __restrict__ W,
                              unsigned short* __restrict__ Wt, int K) {
    int t = blockIdx.x * 256 + threadIdx.x;
    if (t < K * 128) {
        int k = t >> 7, n = t & 127;
        Wt[n * K + k] = f2bf(W[t]);
    }
}

// ---------------- h fp32 -> bf16 (contiguous) ----------------
__global__ void h_cvt(const float* __restrict__ h, unsigned short* __restrict__ hbf) {
    int t = blockIdx.x * 256 + threadIdx.x;   // 800000 threads, 8 elems each
    const float4* h4 = (const float4*)h;
    float4 a = h4[(size_t)t * 2];
    float4 b = h4[(size_t)t * 2 + 1];
    short8 v = { (short)f2bf(a.x), (short)f2bf(a.y), (short)f2bf(a.z), (short)f2bf(a.w),
                 (short)f2bf(b.x), (short)f2bf(b.y), (short)f2bf(b.z), (short)f2bf(b.w) };
    *(short8*)(&hbf[(size_t)t * 8]) = v;
}

// ================= MFMA path =================
constexpr int XK = 296;  // 288 + 8 pad (592B stride: 16B-aligned, 2-way banks = free)
constexpr int HK = 136;  // 128 + 8 pad (272B stride)
constexpr int NK = 264;  // 256 + 8 pad (528B stride)

template <bool PRECVT>
__global__ __launch_bounds__(256, 4)
void edge_mfma(const float* __restrict__ h,
               const unsigned short* __restrict__ hbf,
               const int* __restrict__ ei,
               const float* __restrict__ ea,
               const unsigned short* __restrict__ W1t,  // [128][288] bf16
               const float* __restrict__ b1,
               const unsigned short* __restrict__ W2t,  // [128][128] bf16
               const float* __restrict__ b2,
               float* __restrict__ mi)
{
    // sH (64 x HK shorts = 17.4 KB) aliases into sMem after GEMM1 (reg-resident accs)
    __shared__ unsigned short sMem[64 * XK];   // 37.9 KB -> 4 blocks/CU
    __shared__ int sDst[64];

    const int tid = threadIdx.x;
    const int e0  = blockIdx.x * 64;
    if (tid < 64) sDst[tid] = ei[E_TOTAL + e0 + tid];

    // gather: per edge 32x ushort8 chunks (h_src|h_dst) + 8x float4 chunks (ea)
    const float4* h4   = (const float4*)h;
    const short8* hbf8 = (const short8*)hbf;
    const float4* ea4  = (const float4*)ea;
    #pragma unroll
    for (int it = 0; it < 10; ++it) {
        const int idx = tid + it * 256;        // 64*40 = 2560 chunks
        const int e  = idx / 40;
        const int c  = idx - e * 40;
        const int ge = e0 + e;
        if (c < 32) {
            const int node = (c < 16) ? ei[ge] : ei[E_TOTAL + ge];
            const int cc = c & 15;
            short8 v;
            if (PRECVT) {
                v = hbf8[(size_t)node * 16 + cc];
            } else {
                float4 x = h4[(size_t)node * 32 + cc * 2];
                float4 y = h4[(size_t)node * 32 + cc * 2 + 1];
                v = (short8){ (short)f2bf(x.x), (short)f2bf(x.y), (short)f2bf(x.z), (short)f2bf(x.w),
                              (short)f2bf(y.x), (short)f2bf(y.y), (short)f2bf(y.z), (short)f2bf(y.w) };
            }
            *(short8*)(&sMem[e * XK + c * 8]) = v;   // cols c*8 .. c*8+7
        } else {
            float4 x = ea4[(size_t)ge * 8 + (c - 32)];
            unsigned short* p = &sMem[e * XK + 128 + c * 4];  // cols 256+(c-32)*4
            p[0] = f2bf(x.x); p[1] = f2bf(x.y); p[2] = f2bf(x.z); p[3] = f2bf(x.w);
        }
    }
    __syncthreads();

    const int lane = tid & 63;
    const int w    = tid >> 6;
    const int q    = lane >> 4;
    const int lr   = lane & 15;
    const int n0   = w * 32;            // this wave's 32-col slice

    // ---- GEMM1: [64 x 288] @ [288 x 128] (accs stay in regs) ----
    floatx4 acc[4][2];
    #pragma unroll
    for (int mt = 0; mt < 4; ++mt)
        #pragma unroll
        for (int nt = 0; nt < 2; ++nt)
            acc[mt][nt] = (floatx4){0.f, 0.f, 0.f, 0.f};

    #pragma unroll
    for (int ks = 0; ks < 9; ++ks) {
        const int kb = ks * 32 + q * 8;
        short8 a[4], b[2];
        #pragma unroll
        for (int mt = 0; mt < 4; ++mt)
            a[mt] = *(const short8*)(&sMem[(mt * 16 + lr) * XK + kb]);
        #pragma unroll
        for (int nt = 0; nt < 2; ++nt)
            b[nt] = *(const short8*)(&W1t[(n0 + nt * 16 + lr) * 288 + kb]);
        #pragma unroll
        for (int mt = 0; mt < 4; ++mt)
            #pragma unroll
            for (int nt = 0; nt < 2; ++nt)
                acc[mt][nt] = __builtin_amdgcn_mfma_f32_16x16x32_bf16(
                    a[mt], b[nt], acc[mt][nt], 0, 0, 0);
    }
    __syncthreads();   // all waves done READING sX before sH overwrite

    {
        float bias[2] = { b1[n0 + lr], b1[n0 + 16 + lr] };
        #pragma unroll
        for (int mt = 0; mt < 4; ++mt)
            #pragma unroll
            for (int nt = 0; nt < 2; ++nt)
                #pragma unroll
                for (int r = 0; r < 4; ++r) {
                    float v = fmaxf(acc[mt][nt][r] + bias[nt], 0.f);
                    sMem[(mt * 16 + q * 4 + r) * HK + n0 + nt * 16 + lr] = f2bf(v);
                }
    }
    __syncthreads();

    // ---- GEMM2: [64 x 128] @ [128 x 128] ----
    floatx4 acc2[4][2];
    #pragma unroll
    for (int mt = 0; mt < 4; ++mt)
        #pragma unroll
        for (int nt = 0; nt < 2; ++nt)
            acc2[mt][nt] = (floatx4){0.f, 0.f, 0.f, 0.f};

    #pragma unroll
    for (int ks = 0; ks < 4; ++ks) {
        const int kb = ks * 32 + q * 8;
        short8 a[4], b[2];
        #pragma unroll
        for (int mt = 0; mt < 4; ++mt)
            a[mt] = *(const short8*)(&sMem[(mt * 16 + lr) * HK + kb]);
        #pragma unroll
        for (int nt = 0; nt < 2; ++nt)
            b[nt] = *(const short8*)(&W2t[(n0 + nt * 16 + lr) * 128 + kb]);
        #pragma unroll
        for (int mt = 0; mt < 4; ++mt)
            #pragma unroll
            for (int nt = 0; nt < 2; ++nt)
                acc2[mt][nt] = __builtin_amdgcn_mfma_f32_16x16x32_bf16(
                    a[mt], b[nt], acc2[mt][nt], 0, 0, 0);
    }

    {
        float bias[2] = { b2[n0 + lr], b2[n0 + 16 + lr] };
        #pragma unroll
        for (int mt = 0; mt < 4; ++mt)
            #pragma unroll
            for (int r = 0; r < 4; ++r) {
                const int m   = mt * 16 + q * 4 + r;
                const int dst = sDst[m];
                float* row = &mi[(size_t)dst * 128];
                #pragma unroll
                for (int nt = 0; nt < 2; ++nt)
                    atomicAdd(&row[n0 + nt * 16 + lr], acc2[mt][nt][r] + bias[nt]);
            }
    }
}

__global__ __launch_bounds__(256, 4)
void node_mfma(const float* __restrict__ h,
               const float* __restrict__ mi,
               const unsigned short* __restrict__ W1t,  // [128][256] bf16
               const float* __restrict__ b1,
               const unsigned short* __restrict__ W2t,  // [128][128] bf16
               const float* __restrict__ b2,
               float* __restrict__ out)
{
    __shared__ unsigned short sMem[64 * NK];   // 33.8 KB -> 4 blocks/CU

    const int tid = threadIdx.x;
    const int g0  = blockIdx.x * 64;

    const float4* h4  = (const float4*)h;
    const float4* mi4 = (const float4*)mi;
    #pragma unroll
    for (int it = 0; it < 16; ++it) {
        const int idx = tid + it * 256;    // 64*64 chunks
        const int n  = idx >> 6;
        const int c  = idx & 63;
        const int gn = g0 + n;
        float4 v = make_float4(0.f, 0.f, 0.f, 0.f);
        if (gn < N_TOTAL)
            v = (c < 32) ? h4[(size_t)gn * 32 + c] : mi4[(size_t)gn * 32 + (c - 32)];
        unsigned short* p = &sMem[n * NK + c * 4];
        p[0] = f2bf(v.x); p[1] = f2bf(v.y); p[2] = f2bf(v.z); p[3] = f2bf(v.w);
    }
    __syncthreads();

    const int lane = tid & 63;
    const int w    = tid >> 6;
    const int q    = lane >> 4;
    const int lr   = lane & 15;
    const int n0   = w * 32;

    floatx4 acc[4][2];
    #pragma unroll
    for (int mt = 0; mt < 4; ++mt)
        #pragma unroll
        for (int nt = 0; nt < 2; ++nt)
            acc[mt][nt] = (floatx4){0.f, 0.f, 0.f, 0.f};

    #pragma unroll
    for (int ks = 0; ks < 8; ++ks) {
        const int kb = ks * 32 + q * 8;
        short8 a[4], b[2];
        #pragma unroll
        for (int mt = 0; mt < 4; ++mt)
            a[mt] = *(const short8*)(&sMem[(mt * 16 + lr) * NK + kb]);
        #pragma unroll
        for (int nt = 0; nt < 2; ++nt)
            b[nt] = *(const short8*)(&W1t[(n0 + nt * 16 + lr) * 256 + kb]);
        #pragma unroll
        for (int mt = 0; mt < 4; ++mt)
            #pragma unroll
            for (int nt = 0; nt < 2; ++nt)
                acc[mt][nt] = __builtin_amdgcn_mfma_f32_16x16x32_bf16(
                    a[mt], b[nt], acc[mt][nt], 0, 0, 0);
    }
    __syncthreads();   // done reading sX

    {
        float bias[2] = { b1[n0 + lr], b1[n0 + 16 + lr] };
        #pragma unroll
        for (int mt = 0; mt < 4; ++mt)
            #pragma unroll
            for (int nt = 0; nt < 2; ++nt)
                #pragma unroll
                for (int r = 0; r < 4; ++r) {
                    float v = fmaxf(acc[mt][nt][r] + bias[nt], 0.f);
                    sMem[(mt * 16 + q * 4 + r) * HK + n0 + nt * 16 + lr] = f2bf(v);
                }
    }
    __syncthreads();

    floatx4 acc2[4][2];
    #pragma unroll
    for (int mt = 0; mt < 4; ++mt)
        #pragma unroll
        for (int nt = 0; nt < 2; ++nt)
            acc2[mt][nt] = (floatx4){0.f, 0.f, 0.f, 0.f};

    #pragma unroll
    for (int ks = 0; ks < 4; ++ks) {
        const int kb = ks * 32 + q * 8;
        short8 a[4], b[2];
        #pragma unroll
        for (int mt = 0; mt < 4; ++mt)
            a[mt] = *(const short8*)(&sMem[(mt * 16 + lr) * HK + kb]);
        #pragma unroll
        for (int nt = 0; nt < 2; ++nt)
            b[nt] = *(const short8*)(&W2t[(n0 + nt * 16 + lr) * 128 + kb]);
        #pragma unroll
        for (int mt = 0; mt < 4; ++mt)
            #pragma unroll
            for (int nt = 0; nt < 2; ++nt)
                acc2[mt][nt] = __builtin_amdgcn_mfma_f32_16x16x32_bf16(
                    a[mt], b[nt], acc2[mt][nt], 0, 0, 0);
    }

    {
        float bias[2] = { b2[n0 + lr], b2[n0 + 16 + lr] };
        #pragma unroll
        for (int mt = 0; mt < 4; ++mt)
            #pragma unroll
            for (int r = 0; r < 4; ++r) {
                const int gm = g0 + mt * 16 + q * 4 + r;
                if (gm < N_TOTAL) {
                    #pragma unroll
                    for (int nt = 0; nt < 2; ++nt)
                        out[(size_t)gm * 128 + n0 + nt * 16 + lr] =
                            acc2[mt][nt][r] + bias[nt];
                }
            }
    }
}

extern "C" void kernel_launch(void* const* d_in, const int* in_sizes, int n_in,
                              void* d_out, int out_size, void* d_ws, size_t ws_size,
                              hipStream_t stream) {
    const float* h   = (const float*)d_in[0];
    const int*   ei  = (const int*)d_in[1];
    const float* ea  = (const float*)d_in[2];
    const float* We1 = (const float*)d_in[3];
    const float* be1 = (const float*)d_in[4];
    const float* We2 = (const float*)d_in[5];
    const float* be2 = (const float*)d_in[6];
    const float* Wh1 = (const float*)d_in[7];
    const float* bh1 = (const float*)d_in[8];
    const float* Wh2 = (const float*)d_in[9];
    const float* bh2 = (const float*)d_in[10];
    float* out = (float*)d_out;

    const size_t szMi   = (size_t)N_TOTAL * 128 * sizeof(float);      // 25.6 MB
    const size_t szW1t  = 128 * 288 * 2;
    const size_t szW2t  = 128 * 128 * 2;
    const size_t szWh1t = 128 * 256 * 2;
    const size_t szWh2t = 128 * 128 * 2;
    const size_t szHbf  = (size_t)N_TOTAL * 128 * 2;                  // 12.8 MB
    const size_t offW1t  = szMi;
    const size_t offW2t  = offW1t + szW1t;
    const size_t offWh1t = offW2t + szW2t;
    const size_t offWh2t = offWh1t + szWh1t;
    const size_t offHbf  = offWh2t + szWh2t;
    const size_t needMin  = offHbf;
    const size_t needFull = offHbf + szHbf;

    char* wsb = (char*)d_ws;
    float* mi = (float*)wsb;
    unsigned short* W1t  = (unsigned short*)(wsb + offW1t);
    unsigned short* W2t  = (unsigned short*)(wsb + offW2t);
    unsigned short* Wh1t = (unsigned short*)(wsb + offWh1t);
    unsigned short* Wh2t = (unsigned short*)(wsb + offWh2t);
    unsigned short* hbf  = (unsigned short*)(wsb + offHbf);

    hipMemsetAsync(mi, 0, szMi, stream);
    transpose_cvt<<<(288 * 128 + 255) / 256, 256, 0, stream>>>(We1, W1t, 288);
    transpose_cvt<<<(128 * 128 + 255) / 256, 256, 0, stream>>>(We2, W2t, 128);
    transpose_cvt<<<(256 * 128 + 255) / 256, 256, 0, stream>>>(Wh1, Wh1t, 256);
    transpose_cvt<<<(128 * 128 + 255) / 256, 256, 0, stream>>>(Wh2, Wh2t, 128);

    if (ws_size >= needFull) {
        h_cvt<<<N_TOTAL * 128 / 8 / 256, 256, 0, stream>>>(h, hbf);
        edge_mfma<true><<<E_TOTAL / 64, 256, 0, stream>>>(
            h, hbf, ei, ea, W1t, be1, W2t, be2, mi);
    } else {
        edge_mfma<false><<<E_TOTAL / 64, 256, 0, stream>>>(
            h, nullptr, ei, ea, W1t, be1, W2t, be2, mi);
    }
    node_mfma<<<(N_TOTAL + 63) / 64, 256, 0, stream>>>(
        h, mi, Wh1t, bh1, Wh2t, bh2, out);
    (void)needMin; (void)in_sizes; (void)n_in; (void)out_size;
}

// Round 4
// 618.819 us; speedup vs baseline: 6.0807x; 1.0402x over previous
//
#include <hip/hip_runtime.h>

#define E_TOTAL 800000
#define N_TOTAL 50000

typedef __attribute__((ext_vector_type(8))) short short8;
typedef __attribute__((ext_vector_type(4))) float floatx4;

__device__ __forceinline__ unsigned short f2bf(float f) {
    union { float f; unsigned u; } x; x.f = f;
    unsigned r = x.u + 0x7fff + ((x.u >> 16) & 1);   // RNE
    return (unsigned short)(r >> 16);
}

// ---------------- fused prep: weight transposes + mi zero + h->bf16 ----------------
// blocks [0,400): weight transpose+cvt (102400 elems total)
// blocks [400,6650): zero mi (1.6M float4)
// blocks [6650,9775): h fp32->bf16 (800k threads x 8 elems)
__global__ __launch_bounds__(256)
void prep(const float* __restrict__ We1, const float* __restrict__ We2,
          const float* __restrict__ Wh1, const float* __restrict__ Wh2,
          unsigned short* __restrict__ W1t, unsigned short* __restrict__ W2t,
          unsigned short* __restrict__ Wh1t, unsigned short* __restrict__ Wh2t,
          const float* __restrict__ h, unsigned short* __restrict__ hbf, int do_hbf,
          float* __restrict__ mi)
{
    const int b = blockIdx.x;
    const int tid = threadIdx.x;
    if (b < 400) {
        int t = b * 256 + tid;
        if (t < 36864) {                       // We1 [288][128]
            W1t[(t & 127) * 288 + (t >> 7)] = f2bf(We1[t]);
        } else if (t < 53248) {                // We2 [128][128]
            t -= 36864;
            W2t[(t & 127) * 128 + (t >> 7)] = f2bf(We2[t]);
        } else if (t < 86016) {                // Wh1 [256][128]
            t -= 53248;
            Wh1t[(t & 127) * 256 + (t >> 7)] = f2bf(Wh1[t]);
        } else if (t < 102400) {               // Wh2 [128][128]
            t -= 86016;
            Wh2t[(t & 127) * 128 + (t >> 7)] = f2bf(Wh2[t]);
        }
    } else if (b < 6650) {
        const int t = (b - 400) * 256 + tid;   // 1.6M float4 = 25.6 MB
        ((float4*)mi)[t] = make_float4(0.f, 0.f, 0.f, 0.f);
    } else if (do_hbf) {
        const int t = (b - 6650) * 256 + tid;  // 800k threads
        const float4* h4 = (const float4*)h;
        float4 a = h4[(size_t)t * 2];
        float4 c = h4[(size_t)t * 2 + 1];
        short8 v = { (short)f2bf(a.x), (short)f2bf(a.y), (short)f2bf(a.z), (short)f2bf(a.w),
                     (short)f2bf(c.x), (short)f2bf(c.y), (short)f2bf(c.z), (short)f2bf(c.w) };
        *(short8*)(&hbf[(size_t)t * 8]) = v;
    }
}

// ================= MFMA kernels =================
constexpr int XK = 296;  // 288 + 8 pad (592B stride: 16B-aligned, 2-way banks = free)
constexpr int HK = 136;  // 128 + 8 pad
constexpr int NK = 264;  // 256 + 8 pad

// 32 edges/block, LDS ~19KB -> 8 blocks/CU -> 32 waves/CU
template <bool PRECVT>
__global__ __launch_bounds__(256, 8)
void edge_mfma(const float* __restrict__ h,
               const unsigned short* __restrict__ hbf,
               const int* __restrict__ ei,
               const float* __restrict__ ea,
               const unsigned short* __restrict__ W1t,  // [128][288] bf16
               const float* __restrict__ b1,
               const unsigned short* __restrict__ W2t,  // [128][128] bf16
               const float* __restrict__ b2,
               float* __restrict__ mi)
{
    __shared__ unsigned short sMem[32 * XK];   // 18.9 KB (sH aliases after GEMM1)
    __shared__ int sDst[32];

    const int tid = threadIdx.x;
    const int e0  = blockIdx.x * 32;
    if (tid < 32) sDst[tid] = ei[E_TOTAL + e0 + tid];

    // gather: per edge 32x ushort8 chunks (h_src|h_dst) + 8x float4 (ea) = 40 chunks
    const float4* h4   = (const float4*)h;
    const short8* hbf8 = (const short8*)hbf;
    const float4* ea4  = (const float4*)ea;
    #pragma unroll
    for (int it = 0; it < 5; ++it) {
        const int idx = tid + it * 256;        // 32*40 = 1280 chunks
        const int e  = idx / 40;
        const int c  = idx - e * 40;
        const int ge = e0 + e;
        if (c < 32) {
            const int node = (c < 16) ? ei[ge] : ei[E_TOTAL + ge];
            const int cc = c & 15;
            short8 v;
            if (PRECVT) {
                v = hbf8[(size_t)node * 16 + cc];
            } else {
                float4 x = h4[(size_t)node * 32 + cc * 2];
                float4 y = h4[(size_t)node * 32 + cc * 2 + 1];
                v = (short8){ (short)f2bf(x.x), (short)f2bf(x.y), (short)f2bf(x.z), (short)f2bf(x.w),
                              (short)f2bf(y.x), (short)f2bf(y.y), (short)f2bf(y.z), (short)f2bf(y.w) };
            }
            *(short8*)(&sMem[e * XK + c * 8]) = v;
        } else {
            float4 x = ea4[(size_t)ge * 8 + (c - 32)];
            unsigned short* p = &sMem[e * XK + 128 + c * 4];  // cols 256 + (c-32)*4
            p[0] = f2bf(x.x); p[1] = f2bf(x.y); p[2] = f2bf(x.z); p[3] = f2bf(x.w);
        }
    }
    __syncthreads();

    const int lane = tid & 63;
    const int w    = tid >> 6;
    const int q    = lane >> 4;
    const int lr   = lane & 15;
    const int n0   = w * 32;            // this wave's 32-col slice

    // ---- GEMM1: [32 x 288] @ [288 x 128] ----
    floatx4 acc[2][2];
    #pragma unroll
    for (int mt = 0; mt < 2; ++mt)
        #pragma unroll
        for (int nt = 0; nt < 2; ++nt)
            acc[mt][nt] = (floatx4){0.f, 0.f, 0.f, 0.f};

    #pragma unroll
    for (int ks = 0; ks < 9; ++ks) {
        const int kb = ks * 32 + q * 8;
        short8 a[2], b[2];
        #pragma unroll
        for (int mt = 0; mt < 2; ++mt)
            a[mt] = *(const short8*)(&sMem[(mt * 16 + lr) * XK + kb]);
        #pragma unroll
        for (int nt = 0; nt < 2; ++nt)
            b[nt] = *(const short8*)(&W1t[(n0 + nt * 16 + lr) * 288 + kb]);
        #pragma unroll
        for (int mt = 0; mt < 2; ++mt)
            #pragma unroll
            for (int nt = 0; nt < 2; ++nt)
                acc[mt][nt] = __builtin_amdgcn_mfma_f32_16x16x32_bf16(
                    a[mt], b[nt], acc[mt][nt], 0, 0, 0);
    }
    __syncthreads();   // all waves done READING sX before sH overwrite

    {
        float bias[2] = { b1[n0 + lr], b1[n0 + 16 + lr] };
        #pragma unroll
        for (int mt = 0; mt < 2; ++mt)
            #pragma unroll
            for (int nt = 0; nt < 2; ++nt)
                #pragma unroll
                for (int r = 0; r < 4; ++r) {
                    float v = fmaxf(acc[mt][nt][r] + bias[nt], 0.f);
                    sMem[(mt * 16 + q * 4 + r) * HK + n0 + nt * 16 + lr] = f2bf(v);
                }
    }
    __syncthreads();

    // ---- GEMM2: [32 x 128] @ [128 x 128] ----
    floatx4 acc2[2][2];
    #pragma unroll
    for (int mt = 0; mt < 2; ++mt)
        #pragma unroll
        for (int nt = 0; nt < 2; ++nt)
            acc2[mt][nt] = (floatx4){0.f, 0.f, 0.f, 0.f};

    #pragma unroll
    for (int ks = 0; ks < 4; ++ks) {
        const int kb = ks * 32 + q * 8;
        short8 a[2], b[2];
        #pragma unroll
        for (int mt = 0; mt < 2; ++mt)
            a[mt] = *(const short8*)(&sMem[(mt * 16 + lr) * HK + kb]);
        #pragma unroll
        for (int nt = 0; nt < 2; ++nt)
            b[nt] = *(const short8*)(&W2t[(n0 + nt * 16 + lr) * 128 + kb]);
        #pragma unroll
        for (int mt = 0; mt < 2; ++mt)
            #pragma unroll
            for (int nt = 0; nt < 2; ++nt)
                acc2[mt][nt] = __builtin_amdgcn_mfma_f32_16x16x32_bf16(
                    a[mt], b[nt], acc2[mt][nt], 0, 0, 0);
    }

    {
        float bias[2] = { b2[n0 + lr], b2[n0 + 16 + lr] };
        #pragma unroll
        for (int mt = 0; mt < 2; ++mt)
            #pragma unroll
            for (int r = 0; r < 4; ++r) {
                const int m   = mt * 16 + q * 4 + r;
                const int dst = sDst[m];
                float* row = &mi[(size_t)dst * 128];
                #pragma unroll
                for (int nt = 0; nt < 2; ++nt)
                    atomicAdd(&row[n0 + nt * 16 + lr], acc2[mt][nt][r] + bias[nt]);
            }
    }
}

// 32 nodes/block, LDS ~17KB -> 8 blocks/CU
__global__ __launch_bounds__(256, 8)
void node_mfma(const float* __restrict__ h,
               const float* __restrict__ mi,
               const unsigned short* __restrict__ W1t,  // [128][256] bf16
               const float* __restrict__ b1,
               const unsigned short* __restrict__ W2t,  // [128][128] bf16
               const float* __restrict__ b2,
               float* __restrict__ out)
{
    __shared__ unsigned short sMem[32 * NK];   // 16.9 KB

    const int tid = threadIdx.x;
    const int g0  = blockIdx.x * 32;

    const float4* h4  = (const float4*)h;
    const float4* mi4 = (const float4*)mi;
    #pragma unroll
    for (int it = 0; it < 8; ++it) {
        const int idx = tid + it * 256;    // 32*64 chunks
        const int n  = idx >> 6;
        const int c  = idx & 63;
        const int gn = g0 + n;
        float4 v = make_float4(0.f, 0.f, 0.f, 0.f);
        if (gn < N_TOTAL)
            v = (c < 32) ? h4[(size_t)gn * 32 + c] : mi4[(size_t)gn * 32 + (c - 32)];
        unsigned short* p = &sMem[n * NK + c * 4];
        p[0] = f2bf(v.x); p[1] = f2bf(v.y); p[2] = f2bf(v.z); p[3] = f2bf(v.w);
    }
    __syncthreads();

    const int lane = tid & 63;
    const int w    = tid >> 6;
    const int q    = lane >> 4;
    const int lr   = lane & 15;
    const int n0   = w * 32;

    floatx4 acc[2][2];
    #pragma unroll
    for (int mt = 0; mt < 2; ++mt)
        #pragma unroll
        for (int nt = 0; nt < 2; ++nt)
            acc[mt][nt] = (floatx4){0.f, 0.f, 0.f, 0.f};

    #pragma unroll
    for (int ks = 0; ks < 8; ++ks) {
        const int kb = ks * 32 + q * 8;
        short8 a[2], b[2];
        #pragma unroll
        for (int mt = 0; mt < 2; ++mt)
            a[mt] = *(const short8*)(&sMem[(mt * 16 + lr) * NK + kb]);
        #pragma unroll
        for (int nt = 0; nt < 2; ++nt)
            b[nt] = *(const short8*)(&W1t[(n0 + nt * 16 + lr) * 256 + kb]);
        #pragma unroll
        for (int mt = 0; mt < 2; ++mt)
            #pragma unroll
            for (int nt = 0; nt < 2; ++nt)
                acc[mt][nt] = __builtin_amdgcn_mfma_f32_16x16x32_bf16(
                    a[mt], b[nt], acc[mt][nt], 0, 0, 0);
    }
    __syncthreads();   // done reading sX

    {
        float bias[2] = { b1[n0 + lr], b1[n0 + 16 + lr] };
        #pragma unroll
        for (int mt = 0; mt < 2; ++mt)
            #pragma unroll
            for (int nt = 0; nt < 2; ++nt)
                #pragma unroll
                for (int r = 0; r < 4; ++r) {
                    float v = fmaxf(acc[mt][nt][r] + bias[nt], 0.f);
                    sMem[(mt * 16 + q * 4 + r) * HK + n0 + nt * 16 + lr] = f2bf(v);
                }
    }
    __syncthreads();

    floatx4 acc2[2][2];
    #pragma unroll
    for (int mt = 0; mt < 2; ++mt)
        #pragma unroll
        for (int nt = 0; nt < 2; ++nt)
            acc2[mt][nt] = (floatx4){0.f, 0.f, 0.f, 0.f};

    #pragma unroll
    for (int ks = 0; ks < 4; ++ks) {
        const int kb = ks * 32 + q * 8;
        short8 a[2], b[2];
        #pragma unroll
        for (int mt = 0; mt < 2; ++mt)
            a[mt] = *(const short8*)(&sMem[(mt * 16 + lr) * HK + kb]);
        #pragma unroll
        for (int nt = 0; nt < 2; ++nt)
            b[nt] = *(const short8*)(&W2t[(n0 + nt * 16 + lr) * 128 + kb]);
        #pragma unroll
        for (int mt = 0; mt < 2; ++mt)
            #pragma unroll
            for (int nt = 0; nt < 2; ++nt)
                acc2[mt][nt] = __builtin_amdgcn_mfma_f32_16x16x32_bf16(
                    a[mt], b[nt], acc2[mt][nt], 0, 0, 0);
    }

    {
        float bias[2] = { b2[n0 + lr], b2[n0 + 16 + lr] };
        #pragma unroll
        for (int mt = 0; mt < 2; ++mt)
            #pragma unroll
            for (int r = 0; r < 4; ++r) {
                const int gm = g0 + mt * 16 + q * 4 + r;
                if (gm < N_TOTAL) {
                    #pragma unroll
                    for (int nt = 0; nt < 2; ++nt)
                        out[(size_t)gm * 128 + n0 + nt * 16 + lr] =
                            acc2[mt][nt][r] + bias[nt];
                }
            }
    }
}

extern "C" void kernel_launch(void* const* d_in, const int* in_sizes, int n_in,
                              void* d_out, int out_size, void* d_ws, size_t ws_size,
                              hipStream_t stream) {
    const float* h   = (const float*)d_in[0];
    const int*   ei  = (const int*)d_in[1];
    const float* ea  = (const float*)d_in[2];
    const float* We1 = (const float*)d_in[3];
    const float* be1 = (const float*)d_in[4];
    const float* We2 = (const float*)d_in[5];
    const float* be2 = (const float*)d_in[6];
    const float* Wh1 = (const float*)d_in[7];
    const float* bh1 = (const float*)d_in[8];
    const float* Wh2 = (const float*)d_in[9];
    const float* bh2 = (const float*)d_in[10];
    float* out = (float*)d_out;

    const size_t szMi   = (size_t)N_TOTAL * 128 * sizeof(float);      // 25.6 MB
    const size_t szW1t  = 128 * 288 * 2;
    const size_t szW2t  = 128 * 128 * 2;
    const size_t szWh1t = 128 * 256 * 2;
    const size_t szWh2t = 128 * 128 * 2;
    const size_t szHbf  = (size_t)N_TOTAL * 128 * 2;                  // 12.8 MB
    const size_t offW1t  = szMi;
    const size_t offW2t  = offW1t + szW1t;
    const size_t offWh1t = offW2t + szW2t;
    const size_t offWh2t = offWh1t + szWh1t;
    const size_t offHbf  = offWh2t + szWh2t;
    const size_t needFull = offHbf + szHbf;

    char* wsb = (char*)d_ws;
    float* mi = (float*)wsb;
    unsigned short* W1t  = (unsigned short*)(wsb + offW1t);
    unsigned short* W2t  = (unsigned short*)(wsb + offW2t);
    unsigned short* Wh1t = (unsigned short*)(wsb + offWh1t);
    unsigned short* Wh2t = (unsigned short*)(wsb + offWh2t);
    unsigned short* hbf  = (unsigned short*)(wsb + offHbf);

    const int do_hbf = (ws_size >= needFull) ? 1 : 0;
    prep<<<9775, 256, 0, stream>>>(We1, We2, Wh1, Wh2, W1t, W2t, Wh1t, Wh2t,
                                   h, hbf, do_hbf, mi);

    if (do_hbf) {
        edge_mfma<true><<<E_TOTAL / 32, 256, 0, stream>>>(
            h, hbf, ei, ea, W1t, be1, W2t, be2, mi);
    } else {
        edge_mfma<false><<<E_TOTAL / 32, 256, 0, stream>>>(
            h, nullptr, ei, ea, W1t, be1, W2t, be2, mi);
    }
    node_mfma<<<(N_TOTAL + 31) / 32, 256, 0, stream>>>(
        h, mi, Wh1t, bh1, Wh2t, bh2, out);
    (void)in_sizes; (void)n_in; (void)out_size;
}

// Round 5
// 605.956 us; speedup vs baseline: 6.2097x; 1.0212x over previous
//
#include <hip/hip_runtime.h>

#define E_TOTAL 800000
#define N_TOTAL 50000
#define NBINS   50176   // 196*256, padded

typedef __attribute__((ext_vector_type(8))) short short8;
typedef __attribute__((ext_vector_type(4))) float floatx4;

__device__ __forceinline__ unsigned short f2bf(float f) {
    union { float f; unsigned u; } x; x.f = f;
    unsigned r = x.u + 0x7fff + ((x.u >> 16) & 1);   // RNE
    return (unsigned short)(r >> 16);
}

// ---------------- fused prep: weight transpose + mi zero + h->bf16 + hist zero ----------------
// blocks [0,400): weight transpose+cvt; [400,6650): zero mi; [6650,9775): h->bf16;
// [9775,9971): zero hist
__global__ __launch_bounds__(256)
void prep(const float* __restrict__ We1, const float* __restrict__ We2,
          const float* __restrict__ Wh1, const float* __restrict__ Wh2,
          unsigned short* __restrict__ W1t, unsigned short* __restrict__ W2t,
          unsigned short* __restrict__ Wh1t, unsigned short* __restrict__ Wh2t,
          const float* __restrict__ h, unsigned short* __restrict__ hbf, int do_full,
          float* __restrict__ mi, int* __restrict__ hist)
{
    const int b = blockIdx.x;
    const int tid = threadIdx.x;
    if (b < 400) {
        int t = b * 256 + tid;
        if (t < 36864) {
            W1t[(t & 127) * 288 + (t >> 7)] = f2bf(We1[t]);
        } else if (t < 53248) {
            t -= 36864;
            W2t[(t & 127) * 128 + (t >> 7)] = f2bf(We2[t]);
        } else if (t < 86016) {
            t -= 53248;
            Wh1t[(t & 127) * 256 + (t >> 7)] = f2bf(Wh1[t]);
        } else if (t < 102400) {
            t -= 86016;
            Wh2t[(t & 127) * 128 + (t >> 7)] = f2bf(Wh2[t]);
        }
    } else if (b < 6650) {
        const int t = (b - 400) * 256 + tid;
        ((float4*)mi)[t] = make_float4(0.f, 0.f, 0.f, 0.f);
    } else if (b < 9775) {
        if (do_full) {
            const int t = (b - 6650) * 256 + tid;
            const float4* h4 = (const float4*)h;
            float4 a = h4[(size_t)t * 2];
            float4 c = h4[(size_t)t * 2 + 1];
            short8 v = { (short)f2bf(a.x), (short)f2bf(a.y), (short)f2bf(a.z), (short)f2bf(a.w),
                         (short)f2bf(c.x), (short)f2bf(c.y), (short)f2bf(c.z), (short)f2bf(c.w) };
            *(short8*)(&hbf[(size_t)t * 8]) = v;
        }
    } else {
        if (do_full) hist[(b - 9775) * 256 + tid] = 0;
    }
}

// ---------------- counting sort of edge ids by dst ----------------
__global__ __launch_bounds__(256) void k_hist(const int* __restrict__ ei, int* __restrict__ hist) {
    const int t = blockIdx.x * 256 + threadIdx.x;
    atomicAdd(&hist[ei[E_TOTAL + t]], 1);
}
__global__ __launch_bounds__(256) void k_scan1(const int* __restrict__ hist, int* __restrict__ partial) {
    __shared__ int s[256];
    s[threadIdx.x] = hist[blockIdx.x * 256 + threadIdx.x];
    __syncthreads();
    for (int off = 128; off > 0; off >>= 1) {
        if (threadIdx.x < off) s[threadIdx.x] += s[threadIdx.x + off];
        __syncthreads();
    }
    if (threadIdx.x == 0) partial[blockIdx.x] = s[0];
}
__global__ void k_scan2(int* __restrict__ partial, int* __restrict__ partialOff) {
    if (threadIdx.x == 0) {
        int run = 0;
        for (int i = 0; i < NBINS / 256; ++i) { partialOff[i] = run; run += partial[i]; }
    }
}
__global__ __launch_bounds__(256)
void k_scan3(const int* __restrict__ hist, const int* __restrict__ partialOff,
             int* __restrict__ cursor) {
    __shared__ int s[256];
    const int t = threadIdx.x, g = blockIdx.x * 256 + t;
    const int v = hist[g];
    s[t] = v; __syncthreads();
    for (int off = 1; off < 256; off <<= 1) {
        int x = (t >= off) ? s[t - off] : 0;
        __syncthreads();
        s[t] += x;
        __syncthreads();
    }
    cursor[g] = partialOff[blockIdx.x] + s[t] - v;   // exclusive prefix
}
__global__ __launch_bounds__(256)
void k_scatter(const int* __restrict__ ei, int* __restrict__ cursor, int* __restrict__ perm) {
    const int t = blockIdx.x * 256 + threadIdx.x;
    const int dst = ei[E_TOTAL + t];
    const int pos = atomicAdd(&cursor[dst], 1);
    perm[pos] = t;
}

// ================= MFMA kernels =================
constexpr int XK = 296;  // 288 + 8 pad
constexpr int HK = 136;  // 128 + 8 pad
constexpr int NK = 264;  // 256 + 8 pad
constexpr int FJ = 132;  // fp32 epilogue tile stride

// ---- sorted edge kernel: 32 sorted edges/block, run-reduced scatter ----
__global__ __launch_bounds__(256, 8)
void edge_mfma_sorted(const unsigned short* __restrict__ hbf,
                      const int* __restrict__ ei,
                      const float* __restrict__ ea,
                      const int* __restrict__ perm,
                      const unsigned short* __restrict__ W1t,  // [128][288]
                      const float* __restrict__ b1,
                      const unsigned short* __restrict__ W2t,  // [128][128]
                      const float* __restrict__ b2,
                      float* __restrict__ mi)
{
    __shared__ alignas(16) unsigned short sMem[32 * XK];  // aliased: sX / sH / sF
    __shared__ int sDst[32];
    __shared__ int sPerm[32];

    const int tid = threadIdx.x;
    const int e0  = blockIdx.x * 32;
    if (tid < 32) {
        const int p = perm[e0 + tid];
        sPerm[tid] = p;
        sDst[tid]  = ei[E_TOTAL + p];
    }
    __syncthreads();

    const short8* hbf8 = (const short8*)hbf;
    const float4* ea4  = (const float4*)ea;
    #pragma unroll
    for (int it = 0; it < 5; ++it) {
        const int idx = tid + it * 256;        // 32*40 chunks
        const int e  = idx / 40;
        const int c  = idx - e * 40;
        const int ep = sPerm[e];
        if (c < 32) {
            const int node = (c < 16) ? ei[ep] : sDst[e];
            const int cc = c & 15;
            short8 v = hbf8[(size_t)node * 16 + cc];
            *(short8*)(&sMem[e * XK + c * 8]) = v;
        } else {
            float4 x = ea4[(size_t)ep * 8 + (c - 32)];
            unsigned short* p = &sMem[e * XK + 128 + c * 4];
            p[0] = f2bf(x.x); p[1] = f2bf(x.y); p[2] = f2bf(x.z); p[3] = f2bf(x.w);
        }
    }
    __syncthreads();

    const int lane = tid & 63;
    const int w    = tid >> 6;
    const int q    = lane >> 4;
    const int lr   = lane & 15;
    const int n0   = w * 32;

    // ---- GEMM1 ----
    floatx4 acc[2][2];
    #pragma unroll
    for (int mt = 0; mt < 2; ++mt)
        #pragma unroll
        for (int nt = 0; nt < 2; ++nt)
            acc[mt][nt] = (floatx4){0.f, 0.f, 0.f, 0.f};

    #pragma unroll
    for (int ks = 0; ks < 9; ++ks) {
        const int kb = ks * 32 + q * 8;
        short8 a[2], b[2];
        #pragma unroll
        for (int mt = 0; mt < 2; ++mt)
            a[mt] = *(const short8*)(&sMem[(mt * 16 + lr) * XK + kb]);
        #pragma unroll
        for (int nt = 0; nt < 2; ++nt)
            b[nt] = *(const short8*)(&W1t[(n0 + nt * 16 + lr) * 288 + kb]);
        #pragma unroll
        for (int mt = 0; mt < 2; ++mt)
            #pragma unroll
            for (int nt = 0; nt < 2; ++nt)
                acc[mt][nt] = __builtin_amdgcn_mfma_f32_16x16x32_bf16(
                    a[mt], b[nt], acc[mt][nt], 0, 0, 0);
    }
    __syncthreads();

    {
        float bias[2] = { b1[n0 + lr], b1[n0 + 16 + lr] };
        #pragma unroll
        for (int mt = 0; mt < 2; ++mt)
            #pragma unroll
            for (int nt = 0; nt < 2; ++nt)
                #pragma unroll
                for (int r = 0; r < 4; ++r) {
                    float v = fmaxf(acc[mt][nt][r] + bias[nt], 0.f);
                    sMem[(mt * 16 + q * 4 + r) * HK + n0 + nt * 16 + lr] = f2bf(v);
                }
    }
    __syncthreads();

    // ---- GEMM2 ----
    floatx4 acc2[2][2];
    #pragma unroll
    for (int mt = 0; mt < 2; ++mt)
        #pragma unroll
        for (int nt = 0; nt < 2; ++nt)
            acc2[mt][nt] = (floatx4){0.f, 0.f, 0.f, 0.f};

    #pragma unroll
    for (int ks = 0; ks < 4; ++ks) {
        const int kb = ks * 32 + q * 8;
        short8 a[2], b[2];
        #pragma unroll
        for (int mt = 0; mt < 2; ++mt)
            a[mt] = *(const short8*)(&sMem[(mt * 16 + lr) * HK + kb]);
        #pragma unroll
        for (int nt = 0; nt < 2; ++nt)
            b[nt] = *(const short8*)(&W2t[(n0 + nt * 16 + lr) * 128 + kb]);
        #pragma unroll
        for (int mt = 0; mt < 2; ++mt)
            #pragma unroll
            for (int nt = 0; nt < 2; ++nt)
                acc2[mt][nt] = __builtin_amdgcn_mfma_f32_16x16x32_bf16(
                    a[mt], b[nt], acc2[mt][nt], 0, 0, 0);
    }
    __syncthreads();   // GEMM2 LDS reads done before fp32 tile overwrite

    // ---- m_ij tile -> LDS (fp32), then run-length-reduced atomics ----
    float* sF = (float*)sMem;   // [32][FJ]
    {
        float bias[2] = { b2[n0 + lr], b2[n0 + 16 + lr] };
        #pragma unroll
        for (int mt = 0; mt < 2; ++mt)
            #pragma unroll
            for (int nt = 0; nt < 2; ++nt)
                #pragma unroll
                for (int r = 0; r < 4; ++r)
                    sF[(mt * 16 + q * 4 + r) * FJ + n0 + nt * 16 + lr] =
                        acc2[mt][nt][r] + bias[nt];
    }
    __syncthreads();

    if (tid < 128) {
        const int j = tid;
        float sum = 0.f;
        for (int r = 0; r < 32; ++r) {
            sum += sF[r * FJ + j];
            const int dst = sDst[r];
            if (r == 31 || sDst[r + 1] != dst) {     // wave-uniform branch
                atomicAdd(&mi[(size_t)dst * 128 + j], sum);
                sum = 0.f;
            }
        }
    }
}

// ---- flat fallback edge kernel (round-4) ----
template <bool PRECVT>
__global__ __launch_bounds__(256, 8)
void edge_mfma_flat(const float* __restrict__ h,
                    const unsigned short* __restrict__ hbf,
                    const int* __restrict__ ei,
                    const float* __restrict__ ea,
                    const unsigned short* __restrict__ W1t,
                    const float* __restrict__ b1,
                    const unsigned short* __restrict__ W2t,
                    const float* __restrict__ b2,
                    float* __restrict__ mi)
{
    __shared__ unsigned short sMem[32 * XK];
    __shared__ int sDst[32];

    const int tid = threadIdx.x;
    const int e0  = blockIdx.x * 32;
    if (tid < 32) sDst[tid] = ei[E_TOTAL + e0 + tid];

    const float4* h4   = (const float4*)h;
    const short8* hbf8 = (const short8*)hbf;
    const float4* ea4  = (const float4*)ea;
    #pragma unroll
    for (int it = 0; it < 5; ++it) {
        const int idx = tid + it * 256;
        const int e  = idx / 40;
        const int c  = idx - e * 40;
        const int ge = e0 + e;
        if (c < 32) {
            const int node = (c < 16) ? ei[ge] : ei[E_TOTAL + ge];
            const int cc = c & 15;
            short8 v;
            if (PRECVT) {
                v = hbf8[(size_t)node * 16 + cc];
            } else {
                float4 x = h4[(size_t)node * 32 + cc * 2];
                float4 y = h4[(size_t)node * 32 + cc * 2 + 1];
                v = (short8){ (short)f2bf(x.x), (short)f2bf(x.y), (short)f2bf(x.z), (short)f2bf(x.w),
                              (short)f2bf(y.x), (short)f2bf(y.y), (short)f2bf(y.z), (short)f2bf(y.w) };
            }
            *(short8*)(&sMem[e * XK + c * 8]) = v;
        } else {
            float4 x = ea4[(size_t)ge * 8 + (c - 32)];
            unsigned short* p = &sMem[e * XK + 128 + c * 4];
            p[0] = f2bf(x.x); p[1] = f2bf(x.y); p[2] = f2bf(x.z); p[3] = f2bf(x.w);
        }
    }
    __syncthreads();

    const int lane = tid & 63;
    const int w    = tid >> 6;
    const int q    = lane >> 4;
    const int lr   = lane & 15;
    const int n0   = w * 32;

    floatx4 acc[2][2];
    #pragma unroll
    for (int mt = 0; mt < 2; ++mt)
        #pragma unroll
        for (int nt = 0; nt < 2; ++nt)
            acc[mt][nt] = (floatx4){0.f, 0.f, 0.f, 0.f};
    #pragma unroll
    for (int ks = 0; ks < 9; ++ks) {
        const int kb = ks * 32 + q * 8;
        short8 a[2], b[2];
        #pragma unroll
        for (int mt = 0; mt < 2; ++mt)
            a[mt] = *(const short8*)(&sMem[(mt * 16 + lr) * XK + kb]);
        #pragma unroll
        for (int nt = 0; nt < 2; ++nt)
            b[nt] = *(const short8*)(&W1t[(n0 + nt * 16 + lr) * 288 + kb]);
        #pragma unroll
        for (int mt = 0; mt < 2; ++mt)
            #pragma unroll
            for (int nt = 0; nt < 2; ++nt)
                acc[mt][nt] = __builtin_amdgcn_mfma_f32_16x16x32_bf16(
                    a[mt], b[nt], acc[mt][nt], 0, 0, 0);
    }
    __syncthreads();
    {
        float bias[2] = { b1[n0 + lr], b1[n0 + 16 + lr] };
        #pragma unroll
        for (int mt = 0; mt < 2; ++mt)
            #pragma unroll
            for (int nt = 0; nt < 2; ++nt)
                #pragma unroll
                for (int r = 0; r < 4; ++r) {
                    float v = fmaxf(acc[mt][nt][r] + bias[nt], 0.f);
                    sMem[(mt * 16 + q * 4 + r) * HK + n0 + nt * 16 + lr] = f2bf(v);
                }
    }
    __syncthreads();
    floatx4 acc2[2][2];
    #pragma unroll
    for (int mt = 0; mt < 2; ++mt)
        #pragma unroll
        for (int nt = 0; nt < 2; ++nt)
            acc2[mt][nt] = (floatx4){0.f, 0.f, 0.f, 0.f};
    #pragma unroll
    for (int ks = 0; ks < 4; ++ks) {
        const int kb = ks * 32 + q * 8;
        short8 a[2], b[2];
        #pragma unroll
        for (int mt = 0; mt < 2; ++mt)
            a[mt] = *(const short8*)(&sMem[(mt * 16 + lr) * HK + kb]);
        #pragma unroll
        for (int nt = 0; nt < 2; ++nt)
            b[nt] = *(const short8*)(&W2t[(n0 + nt * 16 + lr) * 128 + kb]);
        #pragma unroll
        for (int mt = 0; mt < 2; ++mt)
            #pragma unroll
            for (int nt = 0; nt < 2; ++nt)
                acc2[mt][nt] = __builtin_amdgcn_mfma_f32_16x16x32_bf16(
                    a[mt], b[nt], acc2[mt][nt], 0, 0, 0);
    }
    {
        float bias[2] = { b2[n0 + lr], b2[n0 + 16 + lr] };
        #pragma unroll
        for (int mt = 0; mt < 2; ++mt)
            #pragma unroll
            for (int r = 0; r < 4; ++r) {
                const int m   = mt * 16 + q * 4 + r;
                const int dst = sDst[m];
                float* row = &mi[(size_t)dst * 128];
                #pragma unroll
                for (int nt = 0; nt < 2; ++nt)
                    atomicAdd(&row[n0 + nt * 16 + lr], acc2[mt][nt][r] + bias[nt]);
            }
    }
}

// ---- node kernel (unchanged) ----
__global__ __launch_bounds__(256, 8)
void node_mfma(const float* __restrict__ h,
               const float* __restrict__ mi,
               const unsigned short* __restrict__ W1t,
               const float* __restrict__ b1,
               const unsigned short* __restrict__ W2t,
               const float* __restrict__ b2,
               float* __restrict__ out)
{
    __shared__ unsigned short sMem[32 * NK];

    const int tid = threadIdx.x;
    const int g0  = blockIdx.x * 32;

    const float4* h4  = (const float4*)h;
    const float4* mi4 = (const float4*)mi;
    #pragma unroll
    for (int it = 0; it < 8; ++it) {
        const int idx = tid + it * 256;
        const int n  = idx >> 6;
        const int c  = idx & 63;
        const int gn = g0 + n;
        float4 v = make_float4(0.f, 0.f, 0.f, 0.f);
        if (gn < N_TOTAL)
            v = (c < 32) ? h4[(size_t)gn * 32 + c] : mi4[(size_t)gn * 32 + (c - 32)];
        unsigned short* p = &sMem[n * NK + c * 4];
        p[0] = f2bf(v.x); p[1] = f2bf(v.y); p[2] = f2bf(v.z); p[3] = f2bf(v.w);
    }
    __syncthreads();

    const int lane = tid & 63;
    const int w    = tid >> 6;
    const int q    = lane >> 4;
    const int lr   = lane & 15;
    const int n0   = w * 32;

    floatx4 acc[2][2];
    #pragma unroll
    for (int mt = 0; mt < 2; ++mt)
        #pragma unroll
        for (int nt = 0; nt < 2; ++nt)
            acc[mt][nt] = (floatx4){0.f, 0.f, 0.f, 0.f};
    #pragma unroll
    for (int ks = 0; ks < 8; ++ks) {
        const int kb = ks * 32 + q * 8;
        short8 a[2], b[2];
        #pragma unroll
        for (int mt = 0; mt < 2; ++mt)
            a[mt] = *(const short8*)(&sMem[(mt * 16 + lr) * NK + kb]);
        #pragma unroll
        for (int nt = 0; nt < 2; ++nt)
            b[nt] = *(const short8*)(&W1t[(n0 + nt * 16 + lr) * 256 + kb]);
        #pragma unroll
        for (int mt = 0; mt < 2; ++mt)
            #pragma unroll
            for (int nt = 0; nt < 2; ++nt)
                acc[mt][nt] = __builtin_amdgcn_mfma_f32_16x16x32_bf16(
                    a[mt], b[nt], acc[mt][nt], 0, 0, 0);
    }
    __syncthreads();
    {
        float bias[2] = { b1[n0 + lr], b1[n0 + 16 + lr] };
        #pragma unroll
        for (int mt = 0; mt < 2; ++mt)
            #pragma unroll
            for (int nt = 0; nt < 2; ++nt)
                #pragma unroll
                for (int r = 0; r < 4; ++r) {
                    float v = fmaxf(acc[mt][nt][r] + bias[nt], 0.f);
                    sMem[(mt * 16 + q * 4 + r) * HK + n0 + nt * 16 + lr] = f2bf(v);
                }
    }
    __syncthreads();
    floatx4 acc2[2][2];
    #pragma unroll
    for (int mt = 0; mt < 2; ++mt)
        #pragma unroll
        for (int nt = 0; nt < 2; ++nt)
            acc2[mt][nt] = (floatx4){0.f, 0.f, 0.f, 0.f};
    #pragma unroll
    for (int ks = 0; ks < 4; ++ks) {
        const int kb = ks * 32 + q * 8;
        short8 a[2], b[2];
        #pragma unroll
        for (int mt = 0; mt < 2; ++mt)
            a[mt] = *(const short8*)(&sMem[(mt * 16 + lr) * HK + kb]);
        #pragma unroll
        for (int nt = 0; nt < 2; ++nt)
            b[nt] = *(const short8*)(&W2t[(n0 + nt * 16 + lr) * 128 + kb]);
        #pragma unroll
        for (int mt = 0; mt < 2; ++mt)
            #pragma unroll
            for (int nt = 0; nt < 2; ++nt)
                acc2[mt][nt] = __builtin_amdgcn_mfma_f32_16x16x32_bf16(
                    a[mt], b[nt], acc2[mt][nt], 0, 0, 0);
    }
    {
        float bias[2] = { b2[n0 + lr], b2[n0 + 16 + lr] };
        #pragma unroll
        for (int mt = 0; mt < 2; ++mt)
            #pragma unroll
            for (int r = 0; r < 4; ++r) {
                const int gm = g0 + mt * 16 + q * 4 + r;
                if (gm < N_TOTAL) {
                    #pragma unroll
                    for (int nt = 0; nt < 2; ++nt)
                        out[(size_t)gm * 128 + n0 + nt * 16 + lr] =
                            acc2[mt][nt][r] + bias[nt];
                }
            }
    }
}

extern "C" void kernel_launch(void* const* d_in, const int* in_sizes, int n_in,
                              void* d_out, int out_size, void* d_ws, size_t ws_size,
                              hipStream_t stream) {
    const float* h   = (const float*)d_in[0];
    const int*   ei  = (const int*)d_in[1];
    const float* ea  = (const float*)d_in[2];
    const float* We1 = (const float*)d_in[3];
    const float* be1 = (const float*)d_in[4];
    const float* We2 = (const float*)d_in[5];
    const float* be2 = (const float*)d_in[6];
    const float* Wh1 = (const float*)d_in[7];
    const float* bh1 = (const float*)d_in[8];
    const float* Wh2 = (const float*)d_in[9];
    const float* bh2 = (const float*)d_in[10];
    float* out = (float*)d_out;

    const size_t szMi   = (size_t)N_TOTAL * 128 * sizeof(float);
    const size_t szW1t  = 128 * 288 * 2;
    const size_t szW2t  = 128 * 128 * 2;
    const size_t szWh1t = 128 * 256 * 2;
    const size_t szWh2t = 128 * 128 * 2;
    const size_t szHbf  = (size_t)N_TOTAL * 128 * 2;
    const size_t szPerm = (size_t)E_TOTAL * 4;
    const size_t szHist = (size_t)NBINS * 4;

    const size_t offW1t  = szMi;
    const size_t offW2t  = offW1t + szW1t;
    const size_t offWh1t = offW2t + szW2t;
    const size_t offWh2t = offWh1t + szWh1t;
    const size_t offHbf  = offWh2t + szWh2t;
    const size_t offPerm = offHbf + szHbf;
    const size_t offHist = offPerm + szPerm;
    const size_t offCur  = offHist + szHist;
    const size_t offP1   = offCur + szHist;
    const size_t offP2   = offP1 + 1024;
    const size_t needFull = offP2 + 1024;
    const size_t needCvt  = offPerm;

    char* wsb = (char*)d_ws;
    float* mi = (float*)wsb;
    unsigned short* W1t  = (unsigned short*)(wsb + offW1t);
    unsigned short* W2t  = (unsigned short*)(wsb + offW2t);
    unsigned short* Wh1t = (unsigned short*)(wsb + offWh1t);
    unsigned short* Wh2t = (unsigned short*)(wsb + offWh2t);
    unsigned short* hbf  = (unsigned short*)(wsb + offHbf);
    int* perm    = (int*)(wsb + offPerm);
    int* hist    = (int*)(wsb + offHist);
    int* cursor  = (int*)(wsb + offCur);
    int* partial = (int*)(wsb + offP1);
    int* poff    = (int*)(wsb + offP2);

    const int full = (ws_size >= needFull) ? 1 : 0;

    prep<<<9971, 256, 0, stream>>>(We1, We2, Wh1, Wh2, W1t, W2t, Wh1t, Wh2t,
                                   h, hbf, full, mi, hist);

    if (full) {
        k_hist<<<E_TOTAL / 256, 256, 0, stream>>>(ei, hist);
        k_scan1<<<NBINS / 256, 256, 0, stream>>>(hist, partial);
        k_scan2<<<1, 64, 0, stream>>>(partial, poff);
        k_scan3<<<NBINS / 256, 256, 0, stream>>>(hist, poff, cursor);
        k_scatter<<<E_TOTAL / 256, 256, 0, stream>>>(ei, cursor, perm);
        edge_mfma_sorted<<<E_TOTAL / 32, 256, 0, stream>>>(
            hbf, ei, ea, perm, W1t, be1, W2t, be2, mi);
    } else if (ws_size >= needCvt + szHbf) {
        // no room for sort buffers but room for hbf
        edge_mfma_flat<true><<<E_TOTAL / 32, 256, 0, stream>>>(
            h, hbf, ei, ea, W1t, be1, W2t, be2, mi);
    } else {
        edge_mfma_flat<false><<<E_TOTAL / 32, 256, 0, stream>>>(
            h, nullptr, ei, ea, W1t, be1, W2t, be2, mi);
    }
    node_mfma<<<(N_TOTAL + 31) / 32, 256, 0, stream>>>(
        h, mi, Wh1t, bh1, Wh2t, bh2, out);
    (void)in_sizes; (void)n_in; (void)out_size;
}